// Round 1
// baseline (1388.547 us; speedup 1.0000x reference)
//
#include <hip/hip_runtime.h>
#include <stdio.h>

// ---------------------------------------------------------------------------
// WindowAttention: x(4,32,64,64,64) f32 -> window partition -> MHA over B axis
// -> out_proj -> mlp -> window reverse. All big GEMMs in bf16 MFMA.
// ---------------------------------------------------------------------------

typedef __attribute__((ext_vector_type(4))) float f32x4;
typedef __attribute__((ext_vector_type(8))) short s16x8;
typedef __attribute__((ext_vector_type(2))) unsigned short u16x2;
typedef __attribute__((ext_vector_type(4))) unsigned short u16x4;

#define NB 4        // batch B (attention seq len)
#define NC 32       // channels
#define NTOK 4096   // N = 16^3 windows
#define ED 2048     // embed dim E
#define NH 16       // heads
#define HD 128      // head dim

__device__ __forceinline__ unsigned short f2bf(float f) {
    union { float f; unsigned int u; } v; v.f = f;
    unsigned int r = (v.u + 0x7fffu + ((v.u >> 16) & 1u)) >> 16;
    return (unsigned short)r;
}
__device__ __forceinline__ float bf2f(unsigned short u) {
    union { unsigned int u; float f; } v; v.u = ((unsigned int)u) << 16;
    return v.f;
}

// ---------------- fp32 -> bf16 convert (weights) ----------------
__global__ void f32_to_bf16_kernel(const float* __restrict__ src,
                                   unsigned short* __restrict__ dst, int n4) {
    int i = blockIdx.x * blockDim.x + threadIdx.x;
    if (i >= n4) return;
    f32x4 v = *(const f32x4*)(src + (size_t)i * 4);
    u16x4 w;
    w.x = f2bf(v.x); w.y = f2bf(v.y); w.z = f2bf(v.z); w.w = f2bf(v.w);
    *(u16x4*)(dst + (size_t)i * 4) = w;
}

// ---------------- window partition: x -> tok (B,N,E) bf16 ----------------
// tok[b, n, c*64 + px*16 + py*4 + pz] = x[b, c, nx*4+px, ny*4+py, nz*4+pz]
// n = nx*256 + ny*16 + nz
__global__ void partition_kernel(const float* __restrict__ x,
                                 unsigned short* __restrict__ tok) {
    int idx = blockIdx.x * blockDim.x + threadIdx.x;   // 8,388,608 threads, 4 elems each
    int m = idx & 15;          // Z/4  (= nz)
    int t = idx >> 4;
    int Y = t & 63; t >>= 6;
    int X = t & 63; t >>= 6;
    int c = t & 31;
    int b = t >> 5;
    f32x4 xv = *(const f32x4*)(x + (size_t)idx * 4);
    int nx = X >> 2, px = X & 3;
    int ny = Y >> 2, py = Y & 3;
    int n = nx * 256 + ny * 16 + m;
    int e = c * 64 + px * 16 + py * 4;
    size_t dst = (size_t)(b * NTOK + n) * ED + e;
    u16x4 w;
    w.x = f2bf(xv.x); w.y = f2bf(xv.y); w.z = f2bf(xv.z); w.w = f2bf(xv.w);
    *(u16x4*)&tok[dst] = w;
}

// ---------------- bf16 GEMM: C[r,j] = sum_k A[r,k]*W[j,k] + bias[j] ----------------
// m97-style: 128x128 tile, BK=64, 4 waves (2x2), global_load_lds width16,
// 16x16x32 bf16 MFMA. M,Nout,K all multiples of 128/64.
template <int OUT_BF16>
__global__ __launch_bounds__(256) void gemm_bt(
    const unsigned short* __restrict__ A,   // M x K bf16
    const unsigned short* __restrict__ W,   // Nout x K bf16
    const float* __restrict__ bias,         // Nout f32
    void* __restrict__ Cv,                  // M x Nout (bf16 or f32)
    int M, int Nout, int K)
{
    __shared__ unsigned short ldsA[128 * 64];
    __shared__ unsigned short ldsW[128 * 64];

    const int tid  = threadIdx.x;
    const int wave = tid >> 6;
    const int lane = tid & 63;
    const int bm = blockIdx.x * 128;
    const int bn = blockIdx.y * 128;
    const int wm = (wave >> 1) * 64;
    const int wn = (wave & 1) * 64;

    f32x4 acc[4][4] = {};

    const int srow = lane >> 3;          // 0..7 row within 8-row chunk
    const int scol = (lane & 7) * 8;     // 8 bf16 = 16B per lane
    const int lrow = lane & 15;
    const int lk   = (lane >> 4) * 8;

    const int nkt = K >> 6;
    for (int kt = 0; kt < nkt; ++kt) {
        const int kbase = kt * 64;
        // stage A and W tiles: 16 chunks of 1KB each (8 rows x 128B)
        #pragma unroll
        for (int q = 0; q < 4; ++q) {
            int chunk = wave * 4 + q;          // wave-uniform
            int row = chunk * 8 + srow;
            const unsigned short* ga = A + (size_t)(bm + row) * K + kbase + scol;
            const unsigned short* gw = W + (size_t)(bn + row) * K + kbase + scol;
            __builtin_amdgcn_global_load_lds(
                (const __attribute__((address_space(1))) void*)ga,
                (__attribute__((address_space(3))) void*)(&ldsA[chunk * 512]),
                16, 0, 0);
            __builtin_amdgcn_global_load_lds(
                (const __attribute__((address_space(1))) void*)gw,
                (__attribute__((address_space(3))) void*)(&ldsW[chunk * 512]),
                16, 0, 0);
        }
        __syncthreads();   // drains vmcnt before barrier -> LDS tile visible

        #pragma unroll
        for (int ks = 0; ks < 2; ++ks) {
            const int k0 = ks * 32 + lk;
            s16x8 af[4], bf[4];
            #pragma unroll
            for (int m = 0; m < 4; ++m)
                af[m] = *(const s16x8*)&ldsA[(wm + m * 16 + lrow) * 64 + k0];
            #pragma unroll
            for (int n = 0; n < 4; ++n)
                bf[n] = *(const s16x8*)&ldsW[(wn + n * 16 + lrow) * 64 + k0];
            #pragma unroll
            for (int m = 0; m < 4; ++m)
                #pragma unroll
                for (int n = 0; n < 4; ++n)
                    acc[m][n] = __builtin_amdgcn_mfma_f32_16x16x32_bf16(
                        af[m], bf[n], acc[m][n], 0, 0, 0);
        }
        __syncthreads();   // all waves done reading before next stage
    }

    // epilogue: C/D layout col=lane&15, row=(lane>>4)*4+reg
    const int col   = lane & 15;
    const int rbase = (lane >> 4) * 4;
    #pragma unroll
    for (int n = 0; n < 4; ++n) {
        int cc = bn + wn + n * 16 + col;
        float bv = bias[cc];
        #pragma unroll
        for (int m = 0; m < 4; ++m) {
            #pragma unroll
            for (int r = 0; r < 4; ++r) {
                int rr = bm + wm + m * 16 + rbase + r;
                float val = acc[m][n][r] + bv;
                if (OUT_BF16)
                    ((unsigned short*)Cv)[(size_t)rr * Nout + cc] = f2bf(val);
                else
                    ((float*)Cv)[(size_t)rr * Nout + cc] = val;
            }
        }
    }
}

// ---------------- attention over B axis: seq=4, batch = N*H ----------------
// qkv: (B, N, 3E) bf16 rows b*N+n. o: (B, N, E) bf16.
__global__ __launch_bounds__(64) void attn_kernel(
    const unsigned short* __restrict__ qkv, unsigned short* __restrict__ o)
{
    const int bid  = blockIdx.x;      // n*NH + h
    const int n    = bid >> 4;
    const int h    = bid & 15;
    const int lane = threadIdx.x;
    const int d0   = lane * 2;        // 64 lanes x 2 dims = 128
    const float scale = 0.0883883476483184405501f;  // 1/sqrt(128)

    float q[4][2], k[4][2], v[4][2];
    #pragma unroll
    for (int b = 0; b < 4; ++b) {
        size_t base = (size_t)(b * NTOK + n) * (3 * ED) + h * HD + d0;
        u16x2 uq = *(const u16x2*)&qkv[base];
        u16x2 uk = *(const u16x2*)&qkv[base + ED];
        u16x2 uv = *(const u16x2*)&qkv[base + 2 * ED];
        q[b][0] = bf2f(uq.x); q[b][1] = bf2f(uq.y);
        k[b][0] = bf2f(uk.x); k[b][1] = bf2f(uk.y);
        v[b][0] = bf2f(uv.x); v[b][1] = bf2f(uv.y);
    }

    float sc[4][4];
    #pragma unroll
    for (int s = 0; s < 4; ++s) {
        #pragma unroll
        for (int t = 0; t < 4; ++t) {
            float p = q[s][0] * k[t][0] + q[s][1] * k[t][1];
            #pragma unroll
            for (int off = 32; off > 0; off >>= 1)
                p += __shfl_xor(p, off, 64);
            sc[s][t] = p * scale;
        }
    }

    #pragma unroll
    for (int s = 0; s < 4; ++s) {
        float mx = fmaxf(fmaxf(sc[s][0], sc[s][1]), fmaxf(sc[s][2], sc[s][3]));
        float e0 = __expf(sc[s][0] - mx);
        float e1 = __expf(sc[s][1] - mx);
        float e2 = __expf(sc[s][2] - mx);
        float e3 = __expf(sc[s][3] - mx);
        float inv = 1.0f / (e0 + e1 + e2 + e3);
        float o0 = (e0 * v[0][0] + e1 * v[1][0] + e2 * v[2][0] + e3 * v[3][0]) * inv;
        float o1 = (e0 * v[0][1] + e1 * v[1][1] + e2 * v[2][1] + e3 * v[3][1]) * inv;
        size_t ob = (size_t)(s * NTOK + n) * ED + h * HD + d0;
        u16x2 ov; ov.x = f2bf(o0); ov.y = f2bf(o1);
        *(u16x2*)&o[ob] = ov;
    }
}

// ---------------- window reverse: o3 (B,N,E) f32 -> out (B,C,64,64,64) ----------------
// out[b,c, px*16+nx, py*16+ny, pz*16+nz] = o3[b*N+n, c*64+px*16+py*4+pz]
__global__ void reverse_kernel(const float* __restrict__ o3,
                               float* __restrict__ out) {
    int idx = blockIdx.x * blockDim.x + threadIdx.x;   // 4 consecutive Z each
    int m = idx & 15;          // Z0/4
    int t = idx >> 4;
    int Y = t & 63; t >>= 6;
    int X = t & 63; t >>= 6;
    int c = t & 31;
    int b = t >> 5;
    int px = X >> 4, nx = X & 15;
    int py = Y >> 4, ny = Y & 15;
    int pz = m >> 2, nz0 = (m & 3) * 4;
    size_t ebase = (size_t)c * 64 + px * 16 + py * 4 + pz;
    f32x4 v;
    #pragma unroll
    for (int i = 0; i < 4; ++i) {
        int n = nx * 256 + ny * 16 + nz0 + i;
        v[i] = o3[(size_t)(b * NTOK + n) * ED + ebase];
    }
    *(f32x4*)(out + (size_t)idx * 4) = v;
}

// ---------------------------------------------------------------------------
extern "C" void kernel_launch(void* const* d_in, const int* in_sizes, int n_in,
                              void* d_out, int out_size, void* d_ws, size_t ws_size,
                              hipStream_t stream) {
    const float* x          = (const float*)d_in[0];
    const float* in_proj_w  = (const float*)d_in[1];
    const float* in_proj_b  = (const float*)d_in[2];
    const float* out_proj_w = (const float*)d_in[3];
    const float* out_proj_b = (const float*)d_in[4];
    const float* mlp_w      = (const float*)d_in[5];
    const float* mlp_b      = (const float*)d_in[6];
    float* out = (float*)d_out;

    const size_t M = 16384;                       // B*N rows
    char* ws = (char*)d_ws;
    size_t off = 0;
    unsigned short* tok   = (unsigned short*)(ws + off); off += M * ED * 2;          // 67MB
    unsigned short* w_in  = (unsigned short*)(ws + off); off += (size_t)3 * ED * ED * 2; // 25MB
    unsigned short* w_out = (unsigned short*)(ws + off); off += (size_t)ED * ED * 2;     // 8MB
    unsigned short* w_mlp = (unsigned short*)(ws + off); off += (size_t)ED * ED * 2;     // 8MB
    unsigned short* obuf  = (unsigned short*)(ws + off); off += M * ED * 2;          // 67MB
    unsigned short* o2buf = (unsigned short*)(ws + off); off += M * ED * 2;          // 67MB
    unsigned short* qkv   = (unsigned short*)(ws + off); off += M * 3 * ED * 2;      // 201MB
    float* o3 = (float*)qkv;   // reuse qkv region after attention (134MB <= 201MB)

    if (ws_size < off) {
        fprintf(stderr, "kernel_launch: ws too small (%zu < %zu)\n", ws_size, off);
        return;
    }

    // weight converts
    {
        int n4 = 3 * ED * ED / 4;
        f32_to_bf16_kernel<<<(n4 + 255) / 256, 256, 0, stream>>>(in_proj_w, w_in, n4);
        n4 = ED * ED / 4;
        f32_to_bf16_kernel<<<(n4 + 255) / 256, 256, 0, stream>>>(out_proj_w, w_out, n4);
        f32_to_bf16_kernel<<<(n4 + 255) / 256, 256, 0, stream>>>(mlp_w, w_mlp, n4);
    }

    // window partition
    partition_kernel<<<(NB * NC * 64 * 64 * 16) / 256, 256, 0, stream>>>(x, tok);

    // qkv = tok @ in_proj_w^T + in_proj_b   (16384 x 6144 x 2048)
    {
        dim3 g(16384 / 128, 6144 / 128);
        gemm_bt<1><<<g, 256, 0, stream>>>(tok, w_in, in_proj_b, qkv, 16384, 6144, 2048);
    }

    // attention (seq=B=4, batch=N*H)
    attn_kernel<<<NTOK * NH, 64, 0, stream>>>(qkv, obuf);

    // o2 = o @ out_proj_w^T + out_proj_b    (16384 x 2048 x 2048)
    {
        dim3 g(16384 / 128, 2048 / 128);
        gemm_bt<1><<<g, 256, 0, stream>>>(obuf, w_out, out_proj_b, o2buf, 16384, 2048, 2048);
        // o3 = o2 @ mlp_w^T + mlp_b (f32 out)
        gemm_bt<0><<<g, 256, 0, stream>>>(o2buf, w_mlp, mlp_b, o3, 16384, 2048, 2048);
    }

    // window reverse
    reverse_kernel<<<(NB * NC * 64 * 64 * 16) / 256, 256, 0, stream>>>(o3, out);
}

// Round 2
// 916.109 us; speedup vs baseline: 1.5157x; 1.5157x over previous
//
#include <hip/hip_runtime.h>
#include <stdio.h>

// ---------------------------------------------------------------------------
// WindowAttention: partition -> QKV gemm -> tiny attention over B axis ->
// out_proj gemm -> mlp gemm -> reverse. GEMMs: 256x256 8-phase bf16 MFMA
// template (T1 XCD swizzle + T2 LDS XOR swizzle + T3/T4 counted vmcnt + T5).
// ---------------------------------------------------------------------------

typedef __attribute__((ext_vector_type(4))) float f32x4;
typedef __attribute__((ext_vector_type(8))) short s16x8;
typedef __attribute__((ext_vector_type(2))) unsigned short u16x2;
typedef __attribute__((ext_vector_type(4))) unsigned short u16x4;

#define NB 4        // batch B (attention seq len)
#define NC 32       // channels
#define NTOK 4096   // N = 16^3 windows
#define ED 2048     // embed dim E
#define NH 16       // heads
#define HD 128      // head dim

__device__ __forceinline__ unsigned short f2bf(float f) {
    union { float f; unsigned int u; } v; v.f = f;
    unsigned int r = (v.u + 0x7fffu + ((v.u >> 16) & 1u)) >> 16;
    return (unsigned short)r;
}
__device__ __forceinline__ float bf2f(unsigned short u) {
    union { unsigned int u; float f; } v; v.u = ((unsigned int)u) << 16;
    return v.f;
}

#define BARRIER() asm volatile("s_barrier" ::: "memory")
#define LGKM0() do { asm volatile("s_waitcnt lgkmcnt(0)" ::: "memory"); \
                     __builtin_amdgcn_sched_barrier(0); } while (0)
#define VMCNT(n) asm volatile("s_waitcnt vmcnt(" #n ")" ::: "memory")

// ---------------- fp32 -> bf16 convert (weights) ----------------
__global__ void f32_to_bf16_kernel(const float* __restrict__ src,
                                   unsigned short* __restrict__ dst, int n4) {
    int i = blockIdx.x * blockDim.x + threadIdx.x;
    if (i >= n4) return;
    f32x4 v = *(const f32x4*)(src + (size_t)i * 4);
    u16x4 w;
    w.x = f2bf(v.x); w.y = f2bf(v.y); w.z = f2bf(v.z); w.w = f2bf(v.w);
    *(u16x4*)(dst + (size_t)i * 4) = w;
}

// ---------------- window partition: x -> tok (B,N,E) bf16 ----------------
__global__ void partition_kernel(const float* __restrict__ x,
                                 unsigned short* __restrict__ tok) {
    int idx = blockIdx.x * blockDim.x + threadIdx.x;
    int m = idx & 15;
    int t = idx >> 4;
    int Y = t & 63; t >>= 6;
    int X = t & 63; t >>= 6;
    int c = t & 31;
    int b = t >> 5;
    f32x4 xv = *(const f32x4*)(x + (size_t)idx * 4);
    int nx = X >> 2, px = X & 3;
    int ny = Y >> 2, py = Y & 3;
    int n = nx * 256 + ny * 16 + m;
    int e = c * 64 + px * 16 + py * 4;
    size_t dst = (size_t)(b * NTOK + n) * ED + e;
    u16x4 w;
    w.x = f2bf(xv.x); w.y = f2bf(xv.y); w.z = f2bf(xv.z); w.w = f2bf(xv.w);
    *(u16x4*)&tok[dst] = w;
}

// ---------------- 256x256 8-phase bf16 GEMM ----------------
// C[r,j] = sum_k A[r,k] * W[j,k] + bias[j].  M,Nout multiples of 256; K of 64.
// 8 waves (2M x 4N), per-wave output 128x64, BK=64, LDS 128KB double-buffered.
// Staging slot schedule (per K-tile t): p1 -> [t+1, A-h1]; p3 -> [t+2, B-h0+h1];
// p4 -> [t+2, A-h0]. vmcnt(6) at p4 guarantees tile t+1 resident.
// LDS swizzle: 16B slot s of row r stored at s ^ (r&7); gload sources are
// pre-swizzled per-lane so the linear lane*16B write lands swizzled.
template <int OUT_BF16>
__global__ __launch_bounds__(512, 2) void gemm256(
    const unsigned short* __restrict__ A,   // M x K bf16
    const unsigned short* __restrict__ W,   // Nout x K bf16
    const float* __restrict__ bias,         // Nout f32
    void* __restrict__ Cv,                  // M x Nout (bf16 or f32)
    int M, int Nout, int K, int gn)
{
    __shared__ unsigned short ldsA[2][2][128 * 64];
    __shared__ unsigned short ldsB[2][2][128 * 64];

    const int tid  = threadIdx.x;
    const int wave = tid >> 6;
    const int lane = tid & 63;

    // T1: bijective XCD swizzle (grid % 8 == 0 for all our shapes)
    const int nwg = gridDim.x;
    const int f   = blockIdx.x;
    const int swz = (f & 7) * (nwg >> 3) + (f >> 3);
    const int bm  = (swz / gn) * 256;
    const int bn  = (swz % gn) * 256;

    const int wi    = wave >> 2;        // 0/1: M half (A LDS half this wave reads)
    const int wj    = wave & 3;         // 0-3: N quarter
    const int bhalf = wj >> 1;          // block-level B half this wave reads
    const int bcol  = (wj & 1) * 64;    // col base within that B half

    const int lrow = lane & 15;
    const int kq   = lane >> 4;                    // 0-3
    const int s0   = ((kq ^ (lrow & 7)) << 3);     // swizzled elem offset, ks=0
    // ks=1 offset: s0 ^ 32

    f32x4 acc[8][4] = {};

    const int nkt = K >> 6;

    // per-wave staging: 2 instrs/half, 8 rows each; row r0+rl, swizzled source
    const int srl   = lane >> 3;                         // 0-7
    const int sslot = (((lane & 7) ^ srl) << 3);         // pre-swizzled elem off

    auto stA = [&](int db, int half, int tt) {
        const unsigned short* gb = A + (size_t)(bm + half * 128) * K + tt * 64;
        unsigned short* lb = &ldsA[db][half][0];
        #pragma unroll
        for (int q = 0; q < 2; ++q) {
            const int r0 = wave * 16 + q * 8;
            const unsigned short* ga = gb + (size_t)(r0 + srl) * K + sslot;
            __builtin_amdgcn_global_load_lds(
                (const __attribute__((address_space(1))) void*)ga,
                (__attribute__((address_space(3))) void*)(lb + r0 * 64),
                16, 0, 0);
        }
    };
    auto stB = [&](int db, int half, int tt) {
        const unsigned short* gb = W + (size_t)(bn + half * 128) * K + tt * 64;
        unsigned short* lb = &ldsB[db][half][0];
        #pragma unroll
        for (int q = 0; q < 2; ++q) {
            const int r0 = wave * 16 + q * 8;
            const unsigned short* ga = gb + (size_t)(r0 + srl) * K + sslot;
            __builtin_amdgcn_global_load_lds(
                (const __attribute__((address_space(1))) void*)ga,
                (__attribute__((address_space(3))) void*)(lb + r0 * 64),
                16, 0, 0);
        }
    };

    // ---- prologue: tile 0 full + tile 1 {B-h0, B-h1, A-h0}
    stA(0, 0, 0); stA(0, 1, 0); stB(0, 0, 0); stB(0, 1, 0);
    stB(1, 0, 1); stB(1, 1, 1); stA(1, 0, 1);
    VMCNT(6);            // tile 0's 8 loads landed (6 of tile 1 outstanding)
    BARRIER();

    for (int t = 0; t < nkt; ++t) {
        const int db = t & 1;
        const unsigned short* hA = &ldsA[db][wi][0];
        const unsigned short* hB = &ldsB[db][bhalf][0];

        s16x8 aL[4][2], aH[4][2], bL[2][2], bH[2][2];

        // ===== phase 1: quadrant (m-low, n-low); stage [t+1, A-h1]
        #pragma unroll
        for (int m = 0; m < 4; ++m) {
            const int rb = (m * 16 + lrow) * 64;
            aL[m][0] = *(const s16x8*)&hA[rb + s0];
            aL[m][1] = *(const s16x8*)&hA[rb + (s0 ^ 32)];
        }
        #pragma unroll
        for (int n = 0; n < 2; ++n) {
            const int rb = (bcol + n * 16 + lrow) * 64;
            bL[n][0] = *(const s16x8*)&hB[rb + s0];
            bL[n][1] = *(const s16x8*)&hB[rb + (s0 ^ 32)];
        }
        if (t + 1 < nkt) stA((t + 1) & 1, 1, t + 1);
        BARRIER(); LGKM0();
        __builtin_amdgcn_s_setprio(1);
        #pragma unroll
        for (int m = 0; m < 4; ++m)
            #pragma unroll
            for (int n = 0; n < 2; ++n) {
                acc[m][n] = __builtin_amdgcn_mfma_f32_16x16x32_bf16(aL[m][0], bL[n][0], acc[m][n], 0, 0, 0);
                acc[m][n] = __builtin_amdgcn_mfma_f32_16x16x32_bf16(aL[m][1], bL[n][1], acc[m][n], 0, 0, 0);
            }
        __builtin_amdgcn_s_setprio(0);
        BARRIER();

        // ===== phase 2: (m-low, n-high); no staging
        #pragma unroll
        for (int n = 0; n < 2; ++n) {
            const int rb = (bcol + (n + 2) * 16 + lrow) * 64;
            bH[n][0] = *(const s16x8*)&hB[rb + s0];
            bH[n][1] = *(const s16x8*)&hB[rb + (s0 ^ 32)];
        }
        BARRIER(); LGKM0();
        __builtin_amdgcn_s_setprio(1);
        #pragma unroll
        for (int m = 0; m < 4; ++m)
            #pragma unroll
            for (int n = 0; n < 2; ++n) {
                acc[m][n + 2] = __builtin_amdgcn_mfma_f32_16x16x32_bf16(aL[m][0], bH[n][0], acc[m][n + 2], 0, 0, 0);
                acc[m][n + 2] = __builtin_amdgcn_mfma_f32_16x16x32_bf16(aL[m][1], bH[n][1], acc[m][n + 2], 0, 0, 0);
            }
        __builtin_amdgcn_s_setprio(0);
        BARRIER();

        // ===== phase 3: (m-high, n-high); stage [t+2, B-h0] + [t+2, B-h1]
        // (B quarters of this buffer were last read in phase 2 -> safe)
        #pragma unroll
        for (int m = 0; m < 4; ++m) {
            const int rb = ((m + 4) * 16 + lrow) * 64;
            aH[m][0] = *(const s16x8*)&hA[rb + s0];
            aH[m][1] = *(const s16x8*)&hA[rb + (s0 ^ 32)];
        }
        if (t + 2 < nkt) { stB(db, 0, t + 2); stB(db, 1, t + 2); }
        BARRIER(); LGKM0();
        __builtin_amdgcn_s_setprio(1);
        #pragma unroll
        for (int m = 0; m < 4; ++m)
            #pragma unroll
            for (int n = 0; n < 2; ++n) {
                acc[m + 4][n + 2] = __builtin_amdgcn_mfma_f32_16x16x32_bf16(aH[m][0], bH[n][0], acc[m + 4][n + 2], 0, 0, 0);
                acc[m + 4][n + 2] = __builtin_amdgcn_mfma_f32_16x16x32_bf16(aH[m][1], bH[n][1], acc[m + 4][n + 2], 0, 0, 0);
            }
        __builtin_amdgcn_s_setprio(0);
        BARRIER();

        // ===== phase 4: (m-high, n-low); stage [t+2, A-h0]; counted vmcnt
        // (A quarters last read in phase 3 -> safe)
        if (t + 2 < nkt) stA(db, 0, t + 2);
        BARRIER();
        __builtin_amdgcn_s_setprio(1);
        #pragma unroll
        for (int m = 0; m < 4; ++m)
            #pragma unroll
            for (int n = 0; n < 2; ++n) {
                acc[m + 4][n] = __builtin_amdgcn_mfma_f32_16x16x32_bf16(aH[m][0], bL[n][0], acc[m + 4][n], 0, 0, 0);
                acc[m + 4][n] = __builtin_amdgcn_mfma_f32_16x16x32_bf16(aH[m][1], bL[n][1], acc[m + 4][n], 0, 0, 0);
            }
        __builtin_amdgcn_s_setprio(0);
        if (t + 2 < nkt)      { VMCNT(6); }   // tile t+1 fully resident
        else if (t + 1 < nkt) { VMCNT(0); }   // epilogue drain for last tile
        BARRIER();
    }

    // ---- epilogue: C/D layout col=lane&15, row=(lane>>4)*4+reg
    const int rowbase = bm + wi * 128 + (kq << 2);
    const int colbase = bn + wj * 64 + lrow;
    #pragma unroll
    for (int n = 0; n < 4; ++n) {
        const int cc = colbase + n * 16;
        const float bv = bias[cc];
        #pragma unroll
        for (int m = 0; m < 8; ++m) {
            #pragma unroll
            for (int r = 0; r < 4; ++r) {
                const int rr = rowbase + m * 16 + r;
                const float val = acc[m][n][r] + bv;
                if (OUT_BF16)
                    ((unsigned short*)Cv)[(size_t)rr * Nout + cc] = f2bf(val);
                else
                    ((float*)Cv)[(size_t)rr * Nout + cc] = val;
            }
        }
    }
}

// ---------------- attention over B axis: seq=4, batch = N*H ----------------
__global__ __launch_bounds__(64) void attn_kernel(
    const unsigned short* __restrict__ qkv, unsigned short* __restrict__ o)
{
    const int bid  = blockIdx.x;      // n*NH + h
    const int n    = bid >> 4;
    const int h    = bid & 15;
    const int lane = threadIdx.x;
    const int d0   = lane * 2;
    const float scale = 0.0883883476483184405501f;  // 1/sqrt(128)

    float q[4][2], k[4][2], v[4][2];
    #pragma unroll
    for (int b = 0; b < 4; ++b) {
        size_t base = (size_t)(b * NTOK + n) * (3 * ED) + h * HD + d0;
        u16x2 uq = *(const u16x2*)&qkv[base];
        u16x2 uk = *(const u16x2*)&qkv[base + ED];
        u16x2 uv = *(const u16x2*)&qkv[base + 2 * ED];
        q[b][0] = bf2f(uq.x); q[b][1] = bf2f(uq.y);
        k[b][0] = bf2f(uk.x); k[b][1] = bf2f(uk.y);
        v[b][0] = bf2f(uv.x); v[b][1] = bf2f(uv.y);
    }

    float sc[4][4];
    #pragma unroll
    for (int s = 0; s < 4; ++s) {
        #pragma unroll
        for (int t = 0; t < 4; ++t) {
            float p = q[s][0] * k[t][0] + q[s][1] * k[t][1];
            #pragma unroll
            for (int off = 32; off > 0; off >>= 1)
                p += __shfl_xor(p, off, 64);
            sc[s][t] = p * scale;
        }
    }

    #pragma unroll
    for (int s = 0; s < 4; ++s) {
        float mx = fmaxf(fmaxf(sc[s][0], sc[s][1]), fmaxf(sc[s][2], sc[s][3]));
        float e0 = __expf(sc[s][0] - mx);
        float e1 = __expf(sc[s][1] - mx);
        float e2 = __expf(sc[s][2] - mx);
        float e3 = __expf(sc[s][3] - mx);
        float inv = 1.0f / (e0 + e1 + e2 + e3);
        float o0 = (e0 * v[0][0] + e1 * v[1][0] + e2 * v[2][0] + e3 * v[3][0]) * inv;
        float o1 = (e0 * v[0][1] + e1 * v[1][1] + e2 * v[2][1] + e3 * v[3][1]) * inv;
        size_t ob = (size_t)(s * NTOK + n) * ED + h * HD + d0;
        u16x2 ov; ov.x = f2bf(o0); ov.y = f2bf(o1);
        *(u16x2*)&o[ob] = ov;
    }
}

// ---------------- window reverse ----------------
__global__ void reverse_kernel(const float* __restrict__ o3,
                               float* __restrict__ out) {
    int idx = blockIdx.x * blockDim.x + threadIdx.x;
    int m = idx & 15;
    int t = idx >> 4;
    int Y = t & 63; t >>= 6;
    int X = t & 63; t >>= 6;
    int c = t & 31;
    int b = t >> 5;
    int px = X >> 4, nx = X & 15;
    int py = Y >> 4, ny = Y & 15;
    int pz = m >> 2, nz0 = (m & 3) * 4;
    size_t ebase = (size_t)c * 64 + px * 16 + py * 4 + pz;
    f32x4 v;
    #pragma unroll
    for (int i = 0; i < 4; ++i) {
        int n = nx * 256 + ny * 16 + nz0 + i;
        v[i] = o3[(size_t)(b * NTOK + n) * ED + ebase];
    }
    *(f32x4*)(out + (size_t)idx * 4) = v;
}

// ---------------------------------------------------------------------------
extern "C" void kernel_launch(void* const* d_in, const int* in_sizes, int n_in,
                              void* d_out, int out_size, void* d_ws, size_t ws_size,
                              hipStream_t stream) {
    const float* x          = (const float*)d_in[0];
    const float* in_proj_w  = (const float*)d_in[1];
    const float* in_proj_b  = (const float*)d_in[2];
    const float* out_proj_w = (const float*)d_in[3];
    const float* out_proj_b = (const float*)d_in[4];
    const float* mlp_w      = (const float*)d_in[5];
    const float* mlp_b      = (const float*)d_in[6];
    float* out = (float*)d_out;

    const size_t M = 16384;                       // B*N rows
    char* ws = (char*)d_ws;
    size_t off = 0;
    unsigned short* tok   = (unsigned short*)(ws + off); off += M * ED * 2;
    unsigned short* w_in  = (unsigned short*)(ws + off); off += (size_t)3 * ED * ED * 2;
    unsigned short* w_out = (unsigned short*)(ws + off); off += (size_t)ED * ED * 2;
    unsigned short* w_mlp = (unsigned short*)(ws + off); off += (size_t)ED * ED * 2;
    unsigned short* obuf  = (unsigned short*)(ws + off); off += M * ED * 2;
    unsigned short* o2buf = (unsigned short*)(ws + off); off += M * ED * 2;
    unsigned short* qkv   = (unsigned short*)(ws + off); off += M * 3 * ED * 2;
    float* o3 = (float*)qkv;   // reuse qkv region after attention

    if (ws_size < off) {
        fprintf(stderr, "kernel_launch: ws too small (%zu < %zu)\n", ws_size, off);
        return;
    }

    // weight converts
    {
        int n4 = 3 * ED * ED / 4;
        f32_to_bf16_kernel<<<(n4 + 255) / 256, 256, 0, stream>>>(in_proj_w, w_in, n4);
        n4 = ED * ED / 4;
        f32_to_bf16_kernel<<<(n4 + 255) / 256, 256, 0, stream>>>(out_proj_w, w_out, n4);
        f32_to_bf16_kernel<<<(n4 + 255) / 256, 256, 0, stream>>>(mlp_w, w_mlp, n4);
    }

    // window partition
    partition_kernel<<<(NB * NC * 64 * 64 * 16) / 256, 256, 0, stream>>>(x, tok);

    // qkv = tok @ in_proj_w^T + in_proj_b   (16384 x 6144 x 2048)
    {
        int gm = 16384 / 256, gn = 6144 / 256;
        gemm256<1><<<dim3(gm * gn), 512, 0, stream>>>(tok, w_in, in_proj_b, qkv,
                                                      16384, 6144, 2048, gn);
    }

    // attention (seq=B=4, batch=N*H)
    attn_kernel<<<NTOK * NH, 64, 0, stream>>>(qkv, obuf);

    // o2 = o @ out_proj_w^T + out_proj_b    (16384 x 2048 x 2048)
    {
        int gm = 16384 / 256, gn = 2048 / 256;
        gemm256<1><<<dim3(gm * gn), 512, 0, stream>>>(obuf, w_out, out_proj_b, o2buf,
                                                      16384, 2048, 2048, gn);
        // o3 = o2 @ mlp_w^T + mlp_b (f32 out)
        gemm256<0><<<dim3(gm * gn), 512, 0, stream>>>(o2buf, w_mlp, mlp_b, o3,
                                                      16384, 2048, 2048, gn);
    }

    // window reverse
    reverse_kernel<<<(NB * NC * 64 * 64 * 16) / 256, 256, 0, stream>>>(o3, out);
}

// Round 3
// 892.038 us; speedup vs baseline: 1.5566x; 1.0270x over previous
//
#include <hip/hip_runtime.h>
#include <stdio.h>

// ---------------------------------------------------------------------------
// WindowAttention: partition -> QKV gemm -> tiny attention over B axis ->
// out_proj gemm -> mlp gemm -> reverse. GEMMs: 256x256 8-phase bf16 MFMA
// template (T2 swizzle + T3/T4 counted vmcnt + T5) + L2-locality macro-tiles.
// ---------------------------------------------------------------------------

typedef __attribute__((ext_vector_type(4))) float f32x4;
typedef __attribute__((ext_vector_type(8))) short s16x8;
typedef __attribute__((ext_vector_type(2))) unsigned short u16x2;
typedef __attribute__((ext_vector_type(4))) unsigned short u16x4;

#define NB 4        // batch B (attention seq len)
#define NC 32       // channels
#define NTOK 4096   // N = 16^3 windows
#define ED 2048     // embed dim E
#define NH 16       // heads
#define HD 128      // head dim

__device__ __forceinline__ unsigned short f2bf(float f) {
    union { float f; unsigned int u; } v; v.f = f;
    unsigned int r = (v.u + 0x7fffu + ((v.u >> 16) & 1u)) >> 16;
    return (unsigned short)r;
}
__device__ __forceinline__ float bf2f(unsigned short u) {
    union { unsigned int u; float f; } v; v.u = ((unsigned int)u) << 16;
    return v.f;
}

#define BARRIER() asm volatile("s_barrier" ::: "memory")
#define LGKM0() do { asm volatile("s_waitcnt lgkmcnt(0)" ::: "memory"); \
                     __builtin_amdgcn_sched_barrier(0); } while (0)
#define VMCNT(n) asm volatile("s_waitcnt vmcnt(" #n ")" ::: "memory")

// ---------------- fp32 -> bf16 convert (weights) ----------------
__global__ void f32_to_bf16_kernel(const float* __restrict__ src,
                                   unsigned short* __restrict__ dst, int n4) {
    int i = blockIdx.x * blockDim.x + threadIdx.x;
    if (i >= n4) return;
    f32x4 v = *(const f32x4*)(src + (size_t)i * 4);
    u16x4 w;
    w.x = f2bf(v.x); w.y = f2bf(v.y); w.z = f2bf(v.z); w.w = f2bf(v.w);
    *(u16x4*)(dst + (size_t)i * 4) = w;
}

// ---------------- window partition: x -> tok (B,N,E) bf16 ----------------
__global__ void partition_kernel(const float* __restrict__ x,
                                 unsigned short* __restrict__ tok) {
    int idx = blockIdx.x * blockDim.x + threadIdx.x;
    int m = idx & 15;
    int t = idx >> 4;
    int Y = t & 63; t >>= 6;
    int X = t & 63; t >>= 6;
    int c = t & 31;
    int b = t >> 5;
    f32x4 xv = *(const f32x4*)(x + (size_t)idx * 4);
    int nx = X >> 2, px = X & 3;
    int ny = Y >> 2, py = Y & 3;
    int n = nx * 256 + ny * 16 + m;
    int e = c * 64 + px * 16 + py * 4;
    size_t dst = (size_t)(b * NTOK + n) * ED + e;
    u16x4 w;
    w.x = f2bf(xv.x); w.y = f2bf(xv.y); w.z = f2bf(xv.z); w.w = f2bf(xv.w);
    *(u16x4*)&tok[dst] = w;
}

// ---------------- 256x256 8-phase bf16 GEMM ----------------
// C[r,j] = sum_k A[r,k] * W[j,k] + bias[j].  Requires M == 16384 (gm=64) and
// Nout % 1024 == 0 (gn % 4 == 0).  8 waves (2M x 4N), per-wave 128x64, BK=64.
// Block mapping: XCD x <- row-band x (8 m-blocks); within band, 8m x 4n
// macro-tiles of 32 blocks = the concurrent set per XCD (L2 working set
// 8 A-panels + 4 B-panels = 12MB, each A shared x4, each B shared x8).
// Staging: p1 -> [t+1, A-h1]; p3 -> [t+2, B]; p4 -> [t+2, A-h0]; vmcnt(6).
// LDS swizzle: 16B slot s of row r at s ^ (r&7); gload sources pre-swizzled.
template <int OUT_BF16>
__global__ __launch_bounds__(512, 2) void gemm256(
    const unsigned short* __restrict__ A,   // M x K bf16
    const unsigned short* __restrict__ W,   // Nout x K bf16
    const float* __restrict__ bias,         // Nout f32
    void* __restrict__ Cv,                  // M x Nout (bf16 or f32)
    int M, int Nout, int K)
{
    __shared__ unsigned short ldsA[2][2][128 * 64];
    __shared__ unsigned short ldsB[2][2][128 * 64];

    const int tid  = threadIdx.x;
    const int wave = tid >> 6;
    const int lane = tid & 63;

    // L2-locality mapping (bijective): f -> (xcd, macro, w) -> (bm, bn)
    const int f   = blockIdx.x;
    const int xcd = f & 7;
    const int r_  = f >> 3;            // rank within XCD, 0..8*gn-1
    const int mac = r_ >> 5;           // macro index along n
    const int w_  = r_ & 31;           // position in 8m x 4n macro
    const int bm  = (xcd * 8 + (w_ & 7)) * 256;
    const int bn  = (mac * 4 + (w_ >> 3)) * 256;

    const int wi    = wave >> 2;        // 0/1: M half
    const int wj    = wave & 3;         // 0-3: N quarter
    const int bhalf = wj >> 1;          // B half this wave reads
    const int bcol  = (wj & 1) * 64;    // col base within that half

    const int lrow = lane & 15;
    const int kq   = lane >> 4;                    // 0-3
    const int s0   = ((kq ^ (lrow & 7)) << 3);     // swizzled elem offset, ks=0

    f32x4 acc[8][4] = {};

    const int nkt = K >> 6;

    const int srl   = lane >> 3;                         // 0-7
    const int sslot = (((lane & 7) ^ srl) << 3);         // pre-swizzled elem off

    auto stA = [&](int db, int half, int tt) {
        const unsigned short* gb = A + (size_t)(bm + half * 128) * K + tt * 64;
        unsigned short* lb = &ldsA[db][half][0];
        #pragma unroll
        for (int q = 0; q < 2; ++q) {
            const int r0 = wave * 16 + q * 8;
            const unsigned short* ga = gb + (size_t)(r0 + srl) * K + sslot;
            __builtin_amdgcn_global_load_lds(
                (const __attribute__((address_space(1))) void*)ga,
                (__attribute__((address_space(3))) void*)(lb + r0 * 64),
                16, 0, 0);
        }
    };
    auto stB = [&](int db, int half, int tt) {
        const unsigned short* gb = W + (size_t)(bn + half * 128) * K + tt * 64;
        unsigned short* lb = &ldsB[db][half][0];
        #pragma unroll
        for (int q = 0; q < 2; ++q) {
            const int r0 = wave * 16 + q * 8;
            const unsigned short* ga = gb + (size_t)(r0 + srl) * K + sslot;
            __builtin_amdgcn_global_load_lds(
                (const __attribute__((address_space(1))) void*)ga,
                (__attribute__((address_space(3))) void*)(lb + r0 * 64),
                16, 0, 0);
        }
    };

    // ---- prologue: tile 0 full + tile 1 {B-h0, B-h1, A-h0}
    stA(0, 0, 0); stA(0, 1, 0); stB(0, 0, 0); stB(0, 1, 0);
    stB(1, 0, 1); stB(1, 1, 1); stA(1, 0, 1);
    VMCNT(6);            // tile 0's 8 loads landed
    BARRIER();

    for (int t = 0; t < nkt; ++t) {
        const int db = t & 1;
        const unsigned short* hA = &ldsA[db][wi][0];
        const unsigned short* hB = &ldsB[db][bhalf][0];

        s16x8 aL[4][2], aH[4][2], bL[2][2], bH[2][2];

        // ===== phase 1: (m-low, n-low); stage [t+1, A-h1]
        #pragma unroll
        for (int m = 0; m < 4; ++m) {
            const int rb = (m * 16 + lrow) * 64;
            aL[m][0] = *(const s16x8*)&hA[rb + s0];
            aL[m][1] = *(const s16x8*)&hA[rb + (s0 ^ 32)];
        }
        #pragma unroll
        for (int n = 0; n < 2; ++n) {
            const int rb = (bcol + n * 16 + lrow) * 64;
            bL[n][0] = *(const s16x8*)&hB[rb + s0];
            bL[n][1] = *(const s16x8*)&hB[rb + (s0 ^ 32)];
        }
        if (t + 1 < nkt) stA((t + 1) & 1, 1, t + 1);
        BARRIER(); LGKM0();
        __builtin_amdgcn_s_setprio(1);
        #pragma unroll
        for (int m = 0; m < 4; ++m)
            #pragma unroll
            for (int n = 0; n < 2; ++n) {
                acc[m][n] = __builtin_amdgcn_mfma_f32_16x16x32_bf16(aL[m][0], bL[n][0], acc[m][n], 0, 0, 0);
                acc[m][n] = __builtin_amdgcn_mfma_f32_16x16x32_bf16(aL[m][1], bL[n][1], acc[m][n], 0, 0, 0);
            }
        __builtin_amdgcn_s_setprio(0);
        BARRIER();

        // ===== phase 2: (m-low, n-high); no staging
        #pragma unroll
        for (int n = 0; n < 2; ++n) {
            const int rb = (bcol + (n + 2) * 16 + lrow) * 64;
            bH[n][0] = *(const s16x8*)&hB[rb + s0];
            bH[n][1] = *(const s16x8*)&hB[rb + (s0 ^ 32)];
        }
        BARRIER(); LGKM0();
        __builtin_amdgcn_s_setprio(1);
        #pragma unroll
        for (int m = 0; m < 4; ++m)
            #pragma unroll
            for (int n = 0; n < 2; ++n) {
                acc[m][n + 2] = __builtin_amdgcn_mfma_f32_16x16x32_bf16(aL[m][0], bH[n][0], acc[m][n + 2], 0, 0, 0);
                acc[m][n + 2] = __builtin_amdgcn_mfma_f32_16x16x32_bf16(aL[m][1], bH[n][1], acc[m][n + 2], 0, 0, 0);
            }
        __builtin_amdgcn_s_setprio(0);
        BARRIER();

        // ===== phase 3: (m-high, n-high); stage [t+2, B-h0] + [t+2, B-h1]
        #pragma unroll
        for (int m = 0; m < 4; ++m) {
            const int rb = ((m + 4) * 16 + lrow) * 64;
            aH[m][0] = *(const s16x8*)&hA[rb + s0];
            aH[m][1] = *(const s16x8*)&hA[rb + (s0 ^ 32)];
        }
        if (t + 2 < nkt) { stB(db, 0, t + 2); stB(db, 1, t + 2); }
        BARRIER(); LGKM0();
        __builtin_amdgcn_s_setprio(1);
        #pragma unroll
        for (int m = 0; m < 4; ++m)
            #pragma unroll
            for (int n = 0; n < 2; ++n) {
                acc[m + 4][n + 2] = __builtin_amdgcn_mfma_f32_16x16x32_bf16(aH[m][0], bH[n][0], acc[m + 4][n + 2], 0, 0, 0);
                acc[m + 4][n + 2] = __builtin_amdgcn_mfma_f32_16x16x32_bf16(aH[m][1], bH[n][1], acc[m + 4][n + 2], 0, 0, 0);
            }
        __builtin_amdgcn_s_setprio(0);
        BARRIER();

        // ===== phase 4: (m-high, n-low); stage [t+2, A-h0]; counted vmcnt
        if (t + 2 < nkt) stA(db, 0, t + 2);
        BARRIER();
        __builtin_amdgcn_s_setprio(1);
        #pragma unroll
        for (int m = 0; m < 4; ++m)
            #pragma unroll
            for (int n = 0; n < 2; ++n) {
                acc[m + 4][n] = __builtin_amdgcn_mfma_f32_16x16x32_bf16(aH[m][0], bL[n][0], acc[m + 4][n], 0, 0, 0);
                acc[m + 4][n] = __builtin_amdgcn_mfma_f32_16x16x32_bf16(aH[m][1], bL[n][1], acc[m + 4][n], 0, 0, 0);
            }
        __builtin_amdgcn_s_setprio(0);
        if (t + 2 < nkt)      { VMCNT(6); }
        else if (t + 1 < nkt) { VMCNT(0); }
        BARRIER();
    }

    // ---- epilogue: col=lane&15, row=(lane>>4)*4+reg; n innermost so the two
    // 32B halves of each 64B C-line are written back-to-back.
    const int rowbase = bm + wi * 128 + (kq << 2);
    const int colbase = bn + wj * 64 + lrow;
    float bv[4];
    #pragma unroll
    for (int n = 0; n < 4; ++n) bv[n] = bias[colbase + n * 16];
    #pragma unroll
    for (int m = 0; m < 8; ++m) {
        #pragma unroll
        for (int r = 0; r < 4; ++r) {
            const int rr = rowbase + m * 16 + r;
            #pragma unroll
            for (int n = 0; n < 4; ++n) {
                const int cc = colbase + n * 16;
                const float val = acc[m][n][r] + bv[n];
                if (OUT_BF16)
                    ((unsigned short*)Cv)[(size_t)rr * Nout + cc] = f2bf(val);
                else
                    ((float*)Cv)[(size_t)rr * Nout + cc] = val;
            }
        }
    }
}

// ---------------- attention over B axis: seq=4, batch = N*H ----------------
__global__ __launch_bounds__(64) void attn_kernel(
    const unsigned short* __restrict__ qkv, unsigned short* __restrict__ o)
{
    const int bid  = blockIdx.x;      // n*NH + h
    const int n    = bid >> 4;
    const int h    = bid & 15;
    const int lane = threadIdx.x;
    const int d0   = lane * 2;
    const float scale = 0.0883883476483184405501f;  // 1/sqrt(128)

    float q[4][2], k[4][2], v[4][2];
    #pragma unroll
    for (int b = 0; b < 4; ++b) {
        size_t base = (size_t)(b * NTOK + n) * (3 * ED) + h * HD + d0;
        u16x2 uq = *(const u16x2*)&qkv[base];
        u16x2 uk = *(const u16x2*)&qkv[base + ED];
        u16x2 uv = *(const u16x2*)&qkv[base + 2 * ED];
        q[b][0] = bf2f(uq.x); q[b][1] = bf2f(uq.y);
        k[b][0] = bf2f(uk.x); k[b][1] = bf2f(uk.y);
        v[b][0] = bf2f(uv.x); v[b][1] = bf2f(uv.y);
    }

    float sc[4][4];
    #pragma unroll
    for (int s = 0; s < 4; ++s) {
        #pragma unroll
        for (int t = 0; t < 4; ++t) {
            float p = q[s][0] * k[t][0] + q[s][1] * k[t][1];
            #pragma unroll
            for (int off = 32; off > 0; off >>= 1)
                p += __shfl_xor(p, off, 64);
            sc[s][t] = p * scale;
        }
    }

    #pragma unroll
    for (int s = 0; s < 4; ++s) {
        float mx = fmaxf(fmaxf(sc[s][0], sc[s][1]), fmaxf(sc[s][2], sc[s][3]));
        float e0 = __expf(sc[s][0] - mx);
        float e1 = __expf(sc[s][1] - mx);
        float e2 = __expf(sc[s][2] - mx);
        float e3 = __expf(sc[s][3] - mx);
        float inv = 1.0f / (e0 + e1 + e2 + e3);
        float o0 = (e0 * v[0][0] + e1 * v[1][0] + e2 * v[2][0] + e3 * v[3][0]) * inv;
        float o1 = (e0 * v[0][1] + e1 * v[1][1] + e2 * v[2][1] + e3 * v[3][1]) * inv;
        size_t ob = (size_t)(s * NTOK + n) * ED + h * HD + d0;
        u16x2 ov; ov.x = f2bf(o0); ov.y = f2bf(o1);
        *(u16x2*)&o[ob] = ov;
    }
}

// ---------------- window reverse (LDS transpose) ----------------
// block = (b, nx, ny): stage 16 token rows of o3 (coalesced), then write
// out[b,c, px*16+nx, py*16+ny, pz*16+nz] as 64B-contiguous Z-runs.
__global__ __launch_bounds__(256) void reverse_kernel(const float* __restrict__ o3,
                                                      float* __restrict__ out) {
    __shared__ float lds[16][2052];   // +4 pad: stride%32 = 4 -> bank spread
    const int t  = threadIdx.x;
    const int b  = blockIdx.x >> 8;
    const int nx = (blockIdx.x >> 4) & 15;
    const int ny = blockIdx.x & 15;
    const int n0 = nx * 256 + ny * 16;

    {   // stage: 16 rows x 2048 f32, fully coalesced
        const int row = t >> 4;
        const int cb  = (t & 15) * 128;
        const float* src = o3 + (size_t)(b * NTOK + n0 + row) * ED + cb;
        #pragma unroll
        for (int i = 0; i < 32; ++i)
            *(f32x4*)&lds[row][cb + i * 4] = *(const f32x4*)&src[i * 4];
    }
    __syncthreads();

    #pragma unroll
    for (int j = 0; j < 2; ++j) {
        const int id = t + j * 256;           // (c, px, py)
        const int py = id & 3, px = (id >> 2) & 3, c = id >> 4;
        const int eb = c * 64 + px * 16 + py * 4;
        f32x4 v[16];
        #pragma unroll
        for (int nz = 0; nz < 16; ++nz)
            v[nz] = *(const f32x4*)&lds[nz][eb];
        float* ob = out + ((size_t)(b * NC + c) * 64 + px * 16 + nx) * 4096
                        + (size_t)(py * 16 + ny) * 64;
        #pragma unroll
        for (int pz = 0; pz < 4; ++pz) {
            float* oz = ob + pz * 16;
            f32x4 w0 = {v[0][pz],  v[1][pz],  v[2][pz],  v[3][pz]};
            f32x4 w1 = {v[4][pz],  v[5][pz],  v[6][pz],  v[7][pz]};
            f32x4 w2 = {v[8][pz],  v[9][pz],  v[10][pz], v[11][pz]};
            f32x4 w3 = {v[12][pz], v[13][pz], v[14][pz], v[15][pz]};
            *(f32x4*)&oz[0]  = w0; *(f32x4*)&oz[4]  = w1;
            *(f32x4*)&oz[8]  = w2; *(f32x4*)&oz[12] = w3;
        }
    }
}

// ---------------------------------------------------------------------------
extern "C" void kernel_launch(void* const* d_in, const int* in_sizes, int n_in,
                              void* d_out, int out_size, void* d_ws, size_t ws_size,
                              hipStream_t stream) {
    const float* x          = (const float*)d_in[0];
    const float* in_proj_w  = (const float*)d_in[1];
    const float* in_proj_b  = (const float*)d_in[2];
    const float* out_proj_w = (const float*)d_in[3];
    const float* out_proj_b = (const float*)d_in[4];
    const float* mlp_w      = (const float*)d_in[5];
    const float* mlp_b      = (const float*)d_in[6];
    float* out = (float*)d_out;

    const size_t M = 16384;                       // B*N rows
    char* ws = (char*)d_ws;
    size_t off = 0;
    unsigned short* tok   = (unsigned short*)(ws + off); off += M * ED * 2;
    unsigned short* w_in  = (unsigned short*)(ws + off); off += (size_t)3 * ED * ED * 2;
    unsigned short* w_out = (unsigned short*)(ws + off); off += (size_t)ED * ED * 2;
    unsigned short* w_mlp = (unsigned short*)(ws + off); off += (size_t)ED * ED * 2;
    unsigned short* obuf  = (unsigned short*)(ws + off); off += M * ED * 2;
    unsigned short* o2buf = (unsigned short*)(ws + off); off += M * ED * 2;
    unsigned short* qkv   = (unsigned short*)(ws + off); off += M * 3 * ED * 2;
    float* o3 = (float*)qkv;   // reuse qkv region after attention

    if (ws_size < off) {
        fprintf(stderr, "kernel_launch: ws too small (%zu < %zu)\n", ws_size, off);
        return;
    }

    // weight converts
    {
        int n4 = 3 * ED * ED / 4;
        f32_to_bf16_kernel<<<(n4 + 255) / 256, 256, 0, stream>>>(in_proj_w, w_in, n4);
        n4 = ED * ED / 4;
        f32_to_bf16_kernel<<<(n4 + 255) / 256, 256, 0, stream>>>(out_proj_w, w_out, n4);
        f32_to_bf16_kernel<<<(n4 + 255) / 256, 256, 0, stream>>>(mlp_w, w_mlp, n4);
    }

    // window partition
    partition_kernel<<<(NB * NC * 64 * 64 * 16) / 256, 256, 0, stream>>>(x, tok);

    // qkv = tok @ in_proj_w^T + in_proj_b   (16384 x 6144 x 2048)
    gemm256<1><<<dim3(64 * (6144 / 256)), 512, 0, stream>>>(
        tok, w_in, in_proj_b, qkv, 16384, 6144, 2048);

    // attention (seq=B=4, batch=N*H)
    attn_kernel<<<NTOK * NH, 64, 0, stream>>>(qkv, obuf);

    // o2 = o @ out_proj_w^T + out_proj_b    (16384 x 2048 x 2048)
    gemm256<1><<<dim3(64 * (2048 / 256)), 512, 0, stream>>>(
        obuf, w_out, out_proj_b, o2buf, 16384, 2048, 2048);
    // o3 = o2 @ mlp_w^T + mlp_b (f32 out)
    gemm256<0><<<dim3(64 * (2048 / 256)), 512, 0, stream>>>(
        o2buf, w_mlp, mlp_b, o3, 16384, 2048, 2048);

    // window reverse
    reverse_kernel<<<NB * 16 * 16, 256, 0, stream>>>(o3, out);
}

// Round 4
// 802.982 us; speedup vs baseline: 1.7292x; 1.1109x over previous
//
#include <hip/hip_runtime.h>
#include <stdio.h>

// ---------------------------------------------------------------------------
// WindowAttention: partition -> QKV gemm -> tiny attention over B axis ->
// fused (out_proj @ mlp) gemm -> reverse.
// Big GEMMs: 256x256 bf16 MFMA, 2-region K-loop, counted vmcnt, LDS swizzle.
// W_comb = mlp_w @ out_proj_w precomputed with a 128^2 MFMA gemm.
// ---------------------------------------------------------------------------

typedef __attribute__((ext_vector_type(4))) float f32x4;
typedef __attribute__((ext_vector_type(8))) short s16x8;
typedef __attribute__((ext_vector_type(2))) unsigned short u16x2;
typedef __attribute__((ext_vector_type(4))) unsigned short u16x4;

#define NB 4        // batch B (attention seq len)
#define NC 32       // channels
#define NTOK 4096   // N = 16^3 windows
#define ED 2048     // embed dim E
#define NH 16       // heads
#define HD 128      // head dim

__device__ __forceinline__ unsigned short f2bf(float f) {
    union { float f; unsigned int u; } v; v.f = f;
    unsigned int r = (v.u + 0x7fffu + ((v.u >> 16) & 1u)) >> 16;
    return (unsigned short)r;
}
__device__ __forceinline__ float bf2f(unsigned short u) {
    union { unsigned int u; float f; } v; v.u = ((unsigned int)u) << 16;
    return v.f;
}

#define BARRIER() asm volatile("s_barrier" ::: "memory")
#define LGKM0() do { asm volatile("s_waitcnt lgkmcnt(0)" ::: "memory"); \
                     __builtin_amdgcn_sched_barrier(0); } while (0)
#define VMCNT(n) asm volatile("s_waitcnt vmcnt(" #n ")" ::: "memory")

// ---------------- fp32 -> bf16 convert (weights) ----------------
__global__ void f32_to_bf16_kernel(const float* __restrict__ src,
                                   unsigned short* __restrict__ dst, int n4) {
    int i = blockIdx.x * blockDim.x + threadIdx.x;
    if (i >= n4) return;
    f32x4 v = *(const f32x4*)(src + (size_t)i * 4);
    u16x4 w;
    w.x = f2bf(v.x); w.y = f2bf(v.y); w.z = f2bf(v.z); w.w = f2bf(v.w);
    *(u16x4*)(dst + (size_t)i * 4) = w;
}

// ---------------- transpose f32 -> bf16: dst[j,k] = src[k,j] ----------------
__global__ __launch_bounds__(256) void transpose_bf16_kernel(
    const float* __restrict__ src, unsigned short* __restrict__ dst, int n) {
    __shared__ float lds[64][68];
    const int bx = blockIdx.x * 64;   // j base
    const int by = blockIdx.y * 64;   // k base
    const int t  = threadIdx.x;
    const int r  = t >> 2;            // 0..63
    const int c4 = (t & 3) * 16;      // 0/16/32/48
    const float* s = src + (size_t)(by + r) * n + bx + c4;
    #pragma unroll
    for (int i = 0; i < 4; ++i)
        *(f32x4*)&lds[r][c4 + i * 4] = *(const f32x4*)(s + i * 4);
    __syncthreads();
    unsigned short* d = dst + (size_t)(bx + r) * n + by + c4;
    #pragma unroll
    for (int i = 0; i < 4; ++i) {
        u16x4 w;
        w.x = f2bf(lds[c4 + i * 4 + 0][r]);
        w.y = f2bf(lds[c4 + i * 4 + 1][r]);
        w.z = f2bf(lds[c4 + i * 4 + 2][r]);
        w.w = f2bf(lds[c4 + i * 4 + 3][r]);
        *(u16x4*)(d + i * 4) = w;
    }
}

// ---------------- b_comb = mlp_w @ out_proj_b + mlp_b ----------------
__global__ void bcomb_kernel(const float* __restrict__ mlp_w,
                             const float* __restrict__ opb,
                             const float* __restrict__ mlpb,
                             float* __restrict__ bcomb) {
    int i = blockIdx.x * blockDim.x + threadIdx.x;   // 0..2047
    const float* row = mlp_w + (size_t)i * ED;
    float s = 0.0f;
    for (int k = 0; k < ED; k += 4) {
        f32x4 a = *(const f32x4*)(row + k);
        f32x4 b = *(const f32x4*)(opb + k);
        s += a.x * b.x + a.y * b.y + a.z * b.z + a.w * b.w;
    }
    bcomb[i] = s + mlpb[i];
}

// ---------------- window partition: x -> tok (B,N,E) bf16 ----------------
__global__ void partition_kernel(const float* __restrict__ x,
                                 unsigned short* __restrict__ tok) {
    int idx = blockIdx.x * blockDim.x + threadIdx.x;
    int m = idx & 15;
    int t = idx >> 4;
    int Y = t & 63; t >>= 6;
    int X = t & 63; t >>= 6;
    int c = t & 31;
    int b = t >> 5;
    f32x4 xv = *(const f32x4*)(x + (size_t)idx * 4);
    int nx = X >> 2, px = X & 3;
    int ny = Y >> 2, py = Y & 3;
    int n = nx * 256 + ny * 16 + m;
    int e = c * 64 + px * 16 + py * 4;
    size_t dst = (size_t)(b * NTOK + n) * ED + e;
    u16x4 w;
    w.x = f2bf(xv.x); w.y = f2bf(xv.y); w.z = f2bf(xv.z); w.w = f2bf(xv.w);
    *(u16x4*)&tok[dst] = w;
}

// ---------------- 128x128 4-wave bf16 GEMM (for small W_comb job) ----------
__global__ __launch_bounds__(256) void gemm128(
    const unsigned short* __restrict__ A,   // M x K bf16
    const unsigned short* __restrict__ W,   // Nout x K bf16
    const float* __restrict__ bias,         // Nout f32
    unsigned short* __restrict__ C,         // M x Nout bf16
    int M, int Nout, int K)
{
    __shared__ unsigned short ldsA[128 * 64];
    __shared__ unsigned short ldsW[128 * 64];

    const int tid  = threadIdx.x;
    const int wave = tid >> 6;
    const int lane = tid & 63;
    const int bm = blockIdx.x * 128;
    const int bn = blockIdx.y * 128;
    const int wm = (wave >> 1) * 64;
    const int wn = (wave & 1) * 64;

    f32x4 acc[4][4] = {};

    const int srow = lane >> 3;
    const int scol = (lane & 7) * 8;
    const int lrow = lane & 15;
    const int lk   = (lane >> 4) * 8;

    const int nkt = K >> 6;
    for (int kt = 0; kt < nkt; ++kt) {
        const int kbase = kt * 64;
        #pragma unroll
        for (int q = 0; q < 4; ++q) {
            int chunk = wave * 4 + q;
            int row = chunk * 8 + srow;
            const unsigned short* ga = A + (size_t)(bm + row) * K + kbase + scol;
            const unsigned short* gw = W + (size_t)(bn + row) * K + kbase + scol;
            __builtin_amdgcn_global_load_lds(
                (const __attribute__((address_space(1))) void*)ga,
                (__attribute__((address_space(3))) void*)(&ldsA[chunk * 512]),
                16, 0, 0);
            __builtin_amdgcn_global_load_lds(
                (const __attribute__((address_space(1))) void*)gw,
                (__attribute__((address_space(3))) void*)(&ldsW[chunk * 512]),
                16, 0, 0);
        }
        __syncthreads();

        #pragma unroll
        for (int ks = 0; ks < 2; ++ks) {
            const int k0 = ks * 32 + lk;
            s16x8 af[4], bf[4];
            #pragma unroll
            for (int m = 0; m < 4; ++m)
                af[m] = *(const s16x8*)&ldsA[(wm + m * 16 + lrow) * 64 + k0];
            #pragma unroll
            for (int n = 0; n < 4; ++n)
                bf[n] = *(const s16x8*)&ldsW[(wn + n * 16 + lrow) * 64 + k0];
            #pragma unroll
            for (int m = 0; m < 4; ++m)
                #pragma unroll
                for (int n = 0; n < 4; ++n)
                    acc[m][n] = __builtin_amdgcn_mfma_f32_16x16x32_bf16(
                        af[m], bf[n], acc[m][n], 0, 0, 0);
        }
        __syncthreads();
    }

    const int col   = lane & 15;
    const int rbase = (lane >> 4) * 4;
    #pragma unroll
    for (int n = 0; n < 4; ++n) {
        int cc = bn + wn + n * 16 + col;
        float bv = bias[cc];
        #pragma unroll
        for (int m = 0; m < 4; ++m)
            #pragma unroll
            for (int r = 0; r < 4; ++r) {
                int rr = bm + wm + m * 16 + rbase + r;
                C[(size_t)rr * Nout + cc] = f2bf(acc[m][n][r] + bv);
            }
    }
}

// ---------------- 256x256 2-region bf16 GEMM ----------------
// C[r,j] = sum_k A[r,k] * W[j,k] + bias[j].  Requires M == 16384 and
// Nout % 1024 == 0.  8 waves (2M x 4N), per-wave 128x64, BK=64, LDS 128KB.
// Per K-tile t (buf db=t&1), ONE barrier per region:
//  region A: read A(16)+bL(4); stage B(t+1)->db^1; lgkm0; 32 MFMA (n0-1); bar
//  region B: read bH(4); stage A(t+2)->db; lgkm0; 32 MFMA (n2-3); vmcnt(4); bar
// Safety: every stage target's last reads completed >=1 barrier earlier;
// vmcnt(4) leaves only A(t+2) in flight -> tile t+1 resident at next region A.
template <int OUT_BF16>
__global__ __launch_bounds__(512, 2) void gemm256(
    const unsigned short* __restrict__ A,   // M x K bf16
    const unsigned short* __restrict__ W,   // Nout x K bf16
    const float* __restrict__ bias,         // Nout f32
    void* __restrict__ Cv,                  // M x Nout (bf16 or f32)
    int M, int Nout, int K)
{
    __shared__ unsigned short ldsA[2][2][128 * 64];
    __shared__ unsigned short ldsB[2][2][128 * 64];

    const int tid  = threadIdx.x;
    const int wave = tid >> 6;
    const int lane = tid & 63;

    // L2-locality mapping (bijective, gm=64): XCD x owns m-band x; 8m x 4n
    // macro-tiles of 32 blocks = the concurrent set per XCD.
    const int f   = blockIdx.x;
    const int xcd = f & 7;
    const int r_  = f >> 3;
    const int mac = r_ >> 5;
    const int w_  = r_ & 31;
    const int bm  = (xcd * 8 + (w_ & 7)) * 256;
    const int bn  = (mac * 4 + (w_ >> 3)) * 256;

    const int wi    = wave >> 2;        // 0/1: M half
    const int wj    = wave & 3;         // 0-3: N quarter
    const int bhalf = wj >> 1;          // B half this wave reads
    const int bcol  = (wj & 1) * 64;    // col base within that half

    const int lrow = lane & 15;
    const int kq   = lane >> 4;                    // 0-3
    const int s0   = ((kq ^ (lrow & 7)) << 3);     // swizzled elem offset

    f32x4 acc[8][4] = {};

    const int nkt = K >> 6;

    const int srl   = lane >> 3;                         // 0-7
    const int sslot = (((lane & 7) ^ srl) << 3);         // pre-swizzled src off

    auto stA = [&](int db, int half, int tt) {
        const unsigned short* gb = A + (size_t)(bm + half * 128) * K + tt * 64;
        unsigned short* lb = &ldsA[db][half][0];
        #pragma unroll
        for (int q = 0; q < 2; ++q) {
            const int r0 = wave * 16 + q * 8;
            const unsigned short* ga = gb + (size_t)(r0 + srl) * K + sslot;
            __builtin_amdgcn_global_load_lds(
                (const __attribute__((address_space(1))) void*)ga,
                (__attribute__((address_space(3))) void*)(lb + r0 * 64),
                16, 0, 0);
        }
    };
    auto stB = [&](int db, int half, int tt) {
        const unsigned short* gb = W + (size_t)(bn + half * 128) * K + tt * 64;
        unsigned short* lb = &ldsB[db][half][0];
        #pragma unroll
        for (int q = 0; q < 2; ++q) {
            const int r0 = wave * 16 + q * 8;
            const unsigned short* ga = gb + (size_t)(r0 + srl) * K + sslot;
            __builtin_amdgcn_global_load_lds(
                (const __attribute__((address_space(1))) void*)ga,
                (__attribute__((address_space(3))) void*)(lb + r0 * 64),
                16, 0, 0);
        }
    };

    // ---- prologue: A(0), B(0), A(1); wait tile 0 (A(1)'s 4 stay in flight)
    stA(0, 0, 0); stA(0, 1, 0);
    stB(0, 0, 0); stB(0, 1, 0);
    stA(1, 0, 1); stA(1, 1, 1);
    VMCNT(4);
    BARRIER();

    for (int t = 0; t < nkt; ++t) {
        const int db = t & 1;
        const unsigned short* hA = &ldsA[db][wi][0];
        const unsigned short* hB = &ldsB[db][bhalf][0];

        s16x8 a[8][2], bl[2][2], bh[2][2];

        // ===== region A: n-quadrants 0-1; stage B(t+1) -> db^1
        #pragma unroll
        for (int m = 0; m < 8; ++m) {
            const int rb = (m * 16 + lrow) * 64;
            a[m][0] = *(const s16x8*)&hA[rb + s0];
            a[m][1] = *(const s16x8*)&hA[rb + (s0 ^ 32)];
        }
        #pragma unroll
        for (int n = 0; n < 2; ++n) {
            const int rb = (bcol + n * 16 + lrow) * 64;
            bl[n][0] = *(const s16x8*)&hB[rb + s0];
            bl[n][1] = *(const s16x8*)&hB[rb + (s0 ^ 32)];
        }
        if (t + 1 < nkt) { stB(db ^ 1, 0, t + 1); stB(db ^ 1, 1, t + 1); }
        LGKM0();
        __builtin_amdgcn_s_setprio(1);
        #pragma unroll
        for (int m = 0; m < 8; ++m)
            #pragma unroll
            for (int n = 0; n < 2; ++n) {
                acc[m][n] = __builtin_amdgcn_mfma_f32_16x16x32_bf16(a[m][0], bl[n][0], acc[m][n], 0, 0, 0);
                acc[m][n] = __builtin_amdgcn_mfma_f32_16x16x32_bf16(a[m][1], bl[n][1], acc[m][n], 0, 0, 0);
            }
        __builtin_amdgcn_s_setprio(0);
        BARRIER();

        // ===== region B: n-quadrants 2-3; stage A(t+2) -> db
        #pragma unroll
        for (int n = 0; n < 2; ++n) {
            const int rb = (bcol + (n + 2) * 16 + lrow) * 64;
            bh[n][0] = *(const s16x8*)&hB[rb + s0];
            bh[n][1] = *(const s16x8*)&hB[rb + (s0 ^ 32)];
        }
        if (t + 2 < nkt) { stA(db, 0, t + 2); stA(db, 1, t + 2); }
        LGKM0();
        __builtin_amdgcn_s_setprio(1);
        #pragma unroll
        for (int m = 0; m < 8; ++m)
            #pragma unroll
            for (int n = 0; n < 2; ++n) {
                acc[m][n + 2] = __builtin_amdgcn_mfma_f32_16x16x32_bf16(a[m][0], bh[n][0], acc[m][n + 2], 0, 0, 0);
                acc[m][n + 2] = __builtin_amdgcn_mfma_f32_16x16x32_bf16(a[m][1], bh[n][1], acc[m][n + 2], 0, 0, 0);
            }
        __builtin_amdgcn_s_setprio(0);
        if (t + 2 < nkt)      { VMCNT(4); }   // tile t+1 fully resident
        else                  { VMCNT(0); }   // drain tail
        BARRIER();
    }

    // ---- epilogue: col=lane&15, row=(lane>>4)*4+reg; n innermost
    const int rowbase = bm + wi * 128 + (kq << 2);
    const int colbase = bn + wj * 64 + lrow;
    float bv[4];
    #pragma unroll
    for (int n = 0; n < 4; ++n) bv[n] = bias[colbase + n * 16];
    #pragma unroll
    for (int m = 0; m < 8; ++m) {
        #pragma unroll
        for (int r = 0; r < 4; ++r) {
            const int rr = rowbase + m * 16 + r;
            #pragma unroll
            for (int n = 0; n < 4; ++n) {
                const int cc = colbase + n * 16;
                const float val = acc[m][n][r] + bv[n];
                if (OUT_BF16)
                    ((unsigned short*)Cv)[(size_t)rr * Nout + cc] = f2bf(val);
                else
                    ((float*)Cv)[(size_t)rr * Nout + cc] = val;
            }
        }
    }
}

// ---------------- attention over B axis: seq=4, batch = N*H ----------------
__global__ __launch_bounds__(64) void attn_kernel(
    const unsigned short* __restrict__ qkv, unsigned short* __restrict__ o)
{
    const int bid  = blockIdx.x;      // n*NH + h
    const int n    = bid >> 4;
    const int h    = bid & 15;
    const int lane = threadIdx.x;
    const int d0   = lane * 2;
    const float scale = 0.0883883476483184405501f;  // 1/sqrt(128)

    float q[4][2], k[4][2], v[4][2];
    #pragma unroll
    for (int b = 0; b < 4; ++b) {
        size_t base = (size_t)(b * NTOK + n) * (3 * ED) + h * HD + d0;
        u16x2 uq = *(const u16x2*)&qkv[base];
        u16x2 uk = *(const u16x2*)&qkv[base + ED];
        u16x2 uv = *(const u16x2*)&qkv[base + 2 * ED];
        q[b][0] = bf2f(uq.x); q[b][1] = bf2f(uq.y);
        k[b][0] = bf2f(uk.x); k[b][1] = bf2f(uk.y);
        v[b][0] = bf2f(uv.x); v[b][1] = bf2f(uv.y);
    }

    float sc[4][4];
    #pragma unroll
    for (int s = 0; s < 4; ++s) {
        #pragma unroll
        for (int t = 0; t < 4; ++t) {
            float p = q[s][0] * k[t][0] + q[s][1] * k[t][1];
            #pragma unroll
            for (int off = 32; off > 0; off >>= 1)
                p += __shfl_xor(p, off, 64);
            sc[s][t] = p * scale;
        }
    }

    #pragma unroll
    for (int s = 0; s < 4; ++s) {
        float mx = fmaxf(fmaxf(sc[s][0], sc[s][1]), fmaxf(sc[s][2], sc[s][3]));
        float e0 = __expf(sc[s][0] - mx);
        float e1 = __expf(sc[s][1] - mx);
        float e2 = __expf(sc[s][2] - mx);
        float e3 = __expf(sc[s][3] - mx);
        float inv = 1.0f / (e0 + e1 + e2 + e3);
        float o0 = (e0 * v[0][0] + e1 * v[1][0] + e2 * v[2][0] + e3 * v[3][0]) * inv;
        float o1 = (e0 * v[0][1] + e1 * v[1][1] + e2 * v[2][1] + e3 * v[3][1]) * inv;
        size_t ob = (size_t)(s * NTOK + n) * ED + h * HD + d0;
        u16x2 ov; ov.x = f2bf(o0); ov.y = f2bf(o1);
        *(u16x2*)&o[ob] = ov;
    }
}

// ---------------- window reverse (LDS transpose) ----------------
__global__ __launch_bounds__(256) void reverse_kernel(const float* __restrict__ o3,
                                                      float* __restrict__ out) {
    __shared__ float lds[16][2052];
    const int t  = threadIdx.x;
    const int b  = blockIdx.x >> 8;
    const int nx = (blockIdx.x >> 4) & 15;
    const int ny = blockIdx.x & 15;
    const int n0 = nx * 256 + ny * 16;

    {
        const int row = t >> 4;
        const int cb  = (t & 15) * 128;
        const float* src = o3 + (size_t)(b * NTOK + n0 + row) * ED + cb;
        #pragma unroll
        for (int i = 0; i < 32; ++i)
            *(f32x4*)&lds[row][cb + i * 4] = *(const f32x4*)&src[i * 4];
    }
    __syncthreads();

    #pragma unroll
    for (int j = 0; j < 2; ++j) {
        const int id = t + j * 256;
        const int py = id & 3, px = (id >> 2) & 3, c = id >> 4;
        const int eb = c * 64 + px * 16 + py * 4;
        f32x4 v[16];
        #pragma unroll
        for (int nz = 0; nz < 16; ++nz)
            v[nz] = *(const f32x4*)&lds[nz][eb];
        float* ob = out + ((size_t)(b * NC + c) * 64 + px * 16 + nx) * 4096
                        + (size_t)(py * 16 + ny) * 64;
        #pragma unroll
        for (int pz = 0; pz < 4; ++pz) {
            float* oz = ob + pz * 16;
            f32x4 w0 = {v[0][pz],  v[1][pz],  v[2][pz],  v[3][pz]};
            f32x4 w1 = {v[4][pz],  v[5][pz],  v[6][pz],  v[7][pz]};
            f32x4 w2 = {v[8][pz],  v[9][pz],  v[10][pz], v[11][pz]};
            f32x4 w3 = {v[12][pz], v[13][pz], v[14][pz], v[15][pz]};
            *(f32x4*)&oz[0]  = w0; *(f32x4*)&oz[4]  = w1;
            *(f32x4*)&oz[8]  = w2; *(f32x4*)&oz[12] = w3;
        }
    }
}

// ---------------------------------------------------------------------------
extern "C" void kernel_launch(void* const* d_in, const int* in_sizes, int n_in,
                              void* d_out, int out_size, void* d_ws, size_t ws_size,
                              hipStream_t stream) {
    const float* x          = (const float*)d_in[0];
    const float* in_proj_w  = (const float*)d_in[1];
    const float* in_proj_b  = (const float*)d_in[2];
    const float* out_proj_w = (const float*)d_in[3];
    const float* out_proj_b = (const float*)d_in[4];
    const float* mlp_w      = (const float*)d_in[5];
    const float* mlp_b      = (const float*)d_in[6];
    float* out = (float*)d_out;

    const size_t M = 16384;                       // B*N rows
    char* ws = (char*)d_ws;
    size_t off = 0;
    unsigned short* tok    = (unsigned short*)(ws + off); off += M * ED * 2;
    unsigned short* w_in   = (unsigned short*)(ws + off); off += (size_t)3 * ED * ED * 2;
    unsigned short* w_mlp  = (unsigned short*)(ws + off); off += (size_t)ED * ED * 2;
    unsigned short* w_outT = (unsigned short*)(ws + off); off += (size_t)ED * ED * 2;
    unsigned short* w_comb = (unsigned short*)(ws + off); off += (size_t)ED * ED * 2;
    float* zbias           = (float*)(ws + off);          off += ED * 4;
    float* b_comb          = (float*)(ws + off);          off += ED * 4;
    unsigned short* obuf   = (unsigned short*)(ws + off); off += M * ED * 2;
    unsigned short* qkv    = (unsigned short*)(ws + off); off += M * 3 * ED * 2;
    float* o3 = (float*)qkv;   // reuse qkv region after attention

    if (ws_size < off) {
        fprintf(stderr, "kernel_launch: ws too small (%zu < %zu)\n", ws_size, off);
        return;
    }

    // weight converts + transpose
    {
        int n4 = 3 * ED * ED / 4;
        f32_to_bf16_kernel<<<(n4 + 255) / 256, 256, 0, stream>>>(in_proj_w, w_in, n4);
        n4 = ED * ED / 4;
        f32_to_bf16_kernel<<<(n4 + 255) / 256, 256, 0, stream>>>(mlp_w, w_mlp, n4);
        transpose_bf16_kernel<<<dim3(ED / 64, ED / 64), 256, 0, stream>>>(
            out_proj_w, w_outT, ED);
        hipMemsetAsync(zbias, 0, ED * sizeof(float), stream);
    }

    // W_comb = mlp_w @ out_proj_w  (row-major [j][k]); 2048^3, 128^2-tile MFMA
    gemm128<<<dim3(ED / 128, ED / 128), 256, 0, stream>>>(
        w_mlp, w_outT, zbias, w_comb, ED, ED, ED);
    // b_comb = mlp_w @ out_proj_b + mlp_b
    bcomb_kernel<<<ED / 256, 256, 0, stream>>>(mlp_w, out_proj_b, mlp_b, b_comb);

    // window partition
    partition_kernel<<<(NB * NC * 64 * 64 * 16) / 256, 256, 0, stream>>>(x, tok);

    // qkv = tok @ in_proj_w^T + in_proj_b   (16384 x 6144 x 2048)
    gemm256<1><<<dim3(64 * (6144 / 256)), 512, 0, stream>>>(
        tok, w_in, in_proj_b, qkv, 16384, 6144, 2048);

    // attention (seq=B=4, batch=N*H)
    attn_kernel<<<NTOK * NH, 64, 0, stream>>>(qkv, obuf);

    // o3 = obuf @ W_comb^T + b_comb  (fused out_proj+mlp, f32 out)
    gemm256<0><<<dim3(64 * (2048 / 256)), 512, 0, stream>>>(
        obuf, w_comb, b_comb, o3, 16384, 2048, 2048);

    // window reverse
    reverse_kernel<<<NB * 16 * 16, 256, 0, stream>>>(o3, out);
}